// Round 2
// baseline (265.601 us; speedup 1.0000x reference)
//
#include <hip/hip_runtime.h>

#define LN 262144
#define LMASK 262143
#define NCH 64
#define NMODE 64
#define TWO_PI 6.2831853071795864769f

// ---------------- K1: forward DFT partial sums ----------------
// grid: nb blocks x 512 threads. Block b handles rows [b*chunk, (b+1)*chunk).
// thread: k = tid&63 (mode, one per lane -> uniform loads per wave),
//         cg = tid>>6 (channel group, 8 channels).
// partials (floats): part[b*8192 +    0 + k*64 + i] = Re sum
//                    part[b*8192 + 4096 + k*64 + i] = Im sum
__global__ __launch_bounds__(512) void fno_fwd(const float* __restrict__ u,
                                               float* __restrict__ part, int nb) {
    const int tid = threadIdx.x;
    const int k = tid & 63;
    const int cg = tid >> 6;
    const int chunk = LN / nb;
    const int n0 = blockIdx.x * chunk;

    float re[8] = {0,0,0,0,0,0,0,0};
    float im[8] = {0,0,0,0,0,0,0,0};

    // per-row rotation step e^{i*2*pi*k/L}; accumulate Re += u*cos, Im -= u*sin
    float ck, sk;
    __sincosf((float)k * (TWO_PI / (float)LN), &sk, &ck);
    float c, s;
    {
        const int ph = (k * n0) & LMASK;
        __sincosf((float)ph * (TWO_PI / (float)LN), &s, &c);
    }

    const float* __restrict__ p = u + (size_t)n0 * NCH + cg * 8;
    #pragma unroll 8
    for (int r = 0; r < chunk; ++r) {
        float4 va = *(const float4*)(p);
        float4 vb = *(const float4*)(p + 4);
        p += NCH;
        float uv[8] = {va.x, va.y, va.z, va.w, vb.x, vb.y, vb.z, vb.w};
        #pragma unroll
        for (int q = 0; q < 8; ++q) {
            re[q] = fmaf(c, uv[q], re[q]);
            im[q] = fmaf(-s, uv[q], im[q]);
        }
        float t = c * ck - s * sk;
        s = fmaf(s, ck, c * sk);
        c = t;
    }

    float* __restrict__ base = part + (size_t)blockIdx.x * 8192 + k * 64 + cg * 8;
    *(float4*)(base)        = make_float4(re[0], re[1], re[2], re[3]);
    *(float4*)(base + 4)    = make_float4(re[4], re[5], re[6], re[7]);
    *(float4*)(base + 4096) = make_float4(im[0], im[1], im[2], im[3]);
    *(float4*)(base + 4100) = make_float4(im[4], im[5], im[6], im[7]);
}

// ---------------- K2: reduce partials + apply Kc + z_local -> coefficients ----------------
// grid: 64 blocks (one per mode k), 256 threads.
// coef[k*64+o]        = A[k][o]  (cos coefficient; k=0 also holds z_local)
// coef[4096 + k*64+o] = B[k][o]  (sin coefficient)
__global__ __launch_bounds__(256) void fno_coef(const float* __restrict__ part, int nb,
                                                const float* __restrict__ Kt,
                                                const float* __restrict__ W,
                                                const float* __restrict__ u,
                                                const float* __restrict__ y,
                                                float* __restrict__ coef) {
    const int k = blockIdx.x;
    const int tid = threadIdx.x;
    const int i = tid & 63;
    const int q = tid >> 6;  // 0..3

    float re = 0.0f, im = 0.0f;
    for (int b = q; b < nb; b += 4) {
        const float* p = part + (size_t)b * 8192 + k * 64 + i;
        re += p[0];
        im += p[4096];
    }
    __shared__ float rs[4][64], is[4][64];
    rs[q][i] = re;
    is[q][i] = im;
    __syncthreads();
    __shared__ float reU[64], imU[64];
    if (tid < 64) {
        reU[tid] = rs[0][tid] + rs[1][tid] + rs[2][tid] + rs[3][tid];
        imU[tid] = is[0][tid] + is[1][tid] + is[2][tid] + is[3][tid];
    }
    __syncthreads();

    if (tid < 64) {
        const int o = tid;
        // z[k][o] = sum_i u_hat[k,i] * (K0[i,o,k] + i*K1[i,o,k])
        float zr = 0.0f, zi = 0.0f;
        for (int ii = 0; ii < 64; ++ii) {
            const float k0v = Kt[(size_t)(ii * 64 + o) * 64 + k];
            const float k1v = Kt[(size_t)262144 + (size_t)(ii * 64 + o) * 64 + k];
            zr += reU[ii] * k0v - imU[ii] * k1v;
            zi += reU[ii] * k1v + imU[ii] * k0v;
        }
        const float invL = 1.0f / (float)LN;
        float A, B;
        if (k == 0) {
            const int idx = (int)(y[0] * (float)LN);
            float zl = 0.0f;
            for (int ii = 0; ii < 64; ++ii)
                zl += W[o * 64 + ii] * u[(size_t)idx * 64 + ii];
            A = zr * invL + zl;   // irfft uses only Re of DC bin; fold z_local here
            B = 0.0f;
        } else {
            A = 2.0f * zr * invL;
            B = -2.0f * zi * invL;
        }
        coef[k * 64 + o] = A;
        coef[4096 + k * 64 + o] = B;
    }
}

// ---------------- K3: inverse (64-mode Fourier series) + write out ----------------
// grid: 1024 blocks x 256 threads; block covers 256 rows.
// thread: cg = tid&7 (channels cg*8..+7), rg = tid>>3 (8 consecutive rows).
// out[n,o] = sum_k A[k][o]*cos(2*pi*k*n/L) + B[k][o]*sin(2*pi*k*n/L)
__global__ __launch_bounds__(256) void fno_inv(const float* __restrict__ coef,
                                               float* __restrict__ out) {
    __shared__ float As[NMODE][NCH];
    __shared__ float Bs[NMODE][NCH];
    const int tid = threadIdx.x;
    for (int e = tid; e < 4096; e += 256) {
        As[e >> 6][e & 63] = coef[e];
        Bs[e >> 6][e & 63] = coef[4096 + e];
    }
    __syncthreads();

    const int cg = tid & 7;
    const int rg = tid >> 3;
    const int n0 = blockIdx.x * 256 + rg * 8;

    float cst[8], sst[8], cr[8], sr[8];
    #pragma unroll
    for (int r = 0; r < 8; ++r) {
        __sincosf((float)(n0 + r) * (TWO_PI / (float)LN), &sst[r], &cst[r]);
        cr[r] = 1.0f;
        sr[r] = 0.0f;
    }
    float acc[8][8];
    #pragma unroll
    for (int r = 0; r < 8; ++r)
        #pragma unroll
        for (int qq = 0; qq < 8; ++qq) acc[r][qq] = 0.0f;

    for (int k = 0; k < NMODE; ++k) {
        float4 a0 = *(const float4*)&As[k][cg * 8];
        float4 a1 = *(const float4*)&As[k][cg * 8 + 4];
        float4 b0 = *(const float4*)&Bs[k][cg * 8];
        float4 b1 = *(const float4*)&Bs[k][cg * 8 + 4];
        float av[8] = {a0.x, a0.y, a0.z, a0.w, a1.x, a1.y, a1.z, a1.w};
        float bv[8] = {b0.x, b0.y, b0.z, b0.w, b1.x, b1.y, b1.z, b1.w};
        #pragma unroll
        for (int r = 0; r < 8; ++r) {
            #pragma unroll
            for (int qq = 0; qq < 8; ++qq)
                acc[r][qq] = fmaf(av[qq], cr[r], fmaf(bv[qq], sr[r], acc[r][qq]));
            float t = cr[r] * cst[r] - sr[r] * sst[r];
            sr[r] = sr[r] * cst[r] + cr[r] * sst[r];
            cr[r] = t;
        }
    }
    #pragma unroll
    for (int r = 0; r < 8; ++r) {
        float* po = out + (size_t)(n0 + r) * NCH + cg * 8;
        *(float4*)(po)     = make_float4(acc[r][0], acc[r][1], acc[r][2], acc[r][3]);
        *(float4*)(po + 4) = make_float4(acc[r][4], acc[r][5], acc[r][6], acc[r][7]);
    }
}

extern "C" void kernel_launch(void* const* d_in, const int* in_sizes, int n_in,
                              void* d_out, int out_size, void* d_ws, size_t ws_size,
                              hipStream_t stream) {
    const float* u = (const float*)d_in[0];
    const float* y = (const float*)d_in[1];
    const float* K = (const float*)d_in[2];
    const float* W = (const float*)d_in[3];
    float* out = (float*)d_out;
    float* ws = (float*)d_ws;

    // choose number of forward blocks (power of two) to fit partials + coef in ws
    int nb = 1024;
    while (nb > 8 && ((size_t)nb * 32768 + 32768) > ws_size) nb >>= 1;

    float* part = ws;                          // nb * 8192 floats
    float* coef = ws + (size_t)nb * 8192;      // 8192 floats

    fno_fwd<<<nb, 512, 0, stream>>>(u, part, nb);
    fno_coef<<<64, 256, 0, stream>>>(part, nb, K, W, u, y, coef);
    fno_inv<<<1024, 256, 0, stream>>>(coef, out);
}

// Round 3
// 73.489 us; speedup vs baseline: 3.6142x; 3.6142x over previous
//
#include <hip/hip_runtime.h>

#define LN 262144
#define LMASK 262143
#define NCH 64
#define INV_L (1.0f/262144.0f)

typedef short short8 __attribute__((ext_vector_type(8)));
typedef float f32x4 __attribute__((ext_vector_type(4)));

static __device__ __forceinline__ unsigned short f2bf(float x) {
    union { float f; unsigned u; } v; v.f = x;
    unsigned r = (v.u + 0x7fff + ((v.u >> 16) & 1)) >> 16;
    return (unsigned short)r;
}
static __device__ __forceinline__ float fsin01(float rev) {  // sin(2*pi*rev)
    float r; asm("v_sin_f32 %0, %1" : "=v"(r) : "v"(rev)); return r;
}
static __device__ __forceinline__ float fcos01(float rev) {  // cos(2*pi*rev)
    float r; asm("v_cos_f32 %0, %1" : "=v"(r) : "v"(rev)); return r;
}

// ---------------- K1: forward DFT partials via MFMA ----------------
// grid: nb x 256 (4 waves). Wave w owns modes 16w..16w+15 (cos tile + sin tile).
// A (trig) generated in-register by complex rotation; B (u tile) staged bf16 in LDS.
// part[b*8192 + k*64 + i] = Re partial, part[b*8192 + 4096 + k*64 + i] = Im partial.
__global__ __launch_bounds__(256) void fno_fwd(const float* __restrict__ u,
                                               float* __restrict__ part, int nb) {
    __shared__ __align__(16) unsigned short Bt[64 * 40];  // [ch][kk], stride 40 bf16
    const int tid = threadIdx.x;
    const int lane = tid & 63;
    const int w = tid >> 6;
    const int chunk = LN / nb;
    const int ksteps = chunk >> 5;
    const int n0 = blockIdx.x * chunk;

    const int kkst = tid >> 3;   // staging row 0..31
    const int gst = tid & 7;     // staging channel group

    const int l15 = lane & 15;
    const int hk = lane >> 4;    // 0..3
    const int m = w * 16 + l15;  // this lane's mode

    // rotation state: 8 (cos,sin) pairs for kk = hk*8 + j
    float cR[8], sR[8];
    #pragma unroll
    for (int j = 0; j < 8; ++j) {
        int kk = hk * 8 + j;
        int ph = (m * (n0 + kk)) & LMASK;
        float rev = (float)ph * INV_L;
        cR[j] = fcos01(rev);
        sR[j] = fsin01(rev);
    }
    float cD, sD;
    {
        int ph = (m * 32) & LMASK;
        float rev = (float)ph * INV_L;
        cD = fcos01(rev);
        sD = fsin01(rev);
    }

    f32x4 accC[4], accS[4];
    #pragma unroll
    for (int t = 0; t < 4; ++t) { accC[t] = (f32x4){0,0,0,0}; accS[t] = (f32x4){0,0,0,0}; }

    const float* pg = u + (size_t)(n0 + kkst) * NCH + gst * 8;
    float4 pa = *(const float4*)pg;
    float4 pb = *(const float4*)(pg + 4);

    for (int t = 0; t < ksteps; ++t) {
        __syncthreads();
        {   // transpose-store current tile as bf16
            float uv[8] = {pa.x, pa.y, pa.z, pa.w, pb.x, pb.y, pb.z, pb.w};
            #pragma unroll
            for (int q = 0; q < 8; ++q)
                Bt[(gst * 8 + q) * 40 + kkst] = f2bf(uv[q]);
        }
        __syncthreads();
        if (t + 1 < ksteps) {   // prefetch next tile (hidden under compute)
            const float* pn = u + (size_t)(n0 + (t + 1) * 32 + kkst) * NCH + gst * 8;
            pa = *(const float4*)pn;
            pb = *(const float4*)(pn + 4);
        }
        // A fragments from rotation state (cos tile, -sin tile)
        short8 aC, aS;
        #pragma unroll
        for (int j = 0; j < 8; ++j) {
            aC[j] = (short)f2bf(cR[j]);
            aS[j] = (short)f2bf(-sR[j]);
        }
        #pragma unroll
        for (int j = 0; j < 8; ++j) {  // advance rotation by 32 rows
            float c2 = cR[j] * cD - sR[j] * sD;
            sR[j] = fmaf(sR[j], cD, cR[j] * sD);
            cR[j] = c2;
        }
        #pragma unroll
        for (int tn = 0; tn < 4; ++tn) {
            const short8 bf = *(const short8*)&Bt[(tn * 16 + l15) * 40 + hk * 8];
            accC[tn] = __builtin_amdgcn_mfma_f32_16x16x32_bf16(aC, bf, accC[tn], 0, 0, 0);
            accS[tn] = __builtin_amdgcn_mfma_f32_16x16x32_bf16(aS, bf, accS[tn], 0, 0, 0);
        }
    }
    // C/D layout: col = lane&15, row = (lane>>4)*4 + reg  [m89-verified]
    float* baseR = part + (size_t)blockIdx.x * 8192;
    #pragma unroll
    for (int tn = 0; tn < 4; ++tn) {
        #pragma unroll
        for (int r = 0; r < 4; ++r) {
            int k = w * 16 + hk * 4 + r;
            int i = tn * 16 + l15;
            baseR[k * 64 + i] = accC[tn][r];
            baseR[4096 + k * 64 + i] = accS[tn][r];
        }
    }
}

// ---------------- K2a: reduce partials (coalesced) ----------------
__global__ __launch_bounds__(256) void fno_red(const float* __restrict__ part, int nb,
                                               float* __restrict__ uhat) {
    __shared__ float sh[2][128];
    const int tid = threadIdx.x;
    const int j = blockIdx.x * 128 + (tid & 127);
    const int h = tid >> 7;
    float s = 0.f;
    #pragma unroll 8
    for (int b = h; b < nb; b += 2)
        s += part[(size_t)b * 8192 + j];
    sh[h][tid & 127] = s;
    __syncthreads();
    if (h == 0) uhat[j] = sh[0][tid] + sh[1][tid];
}

// ---------------- K2b: apply Kc + z_local -> coefficients ----------------
// coef[0..4095]=A (cos coef), coef[4096..8191]=B (sin coef), coef[8192..8255]=z_local
__global__ __launch_bounds__(64) void fno_coef(const float* __restrict__ uhat,
                                               const float* __restrict__ Kt,
                                               const float* __restrict__ W,
                                               const float* __restrict__ u,
                                               const float* __restrict__ y,
                                               float* __restrict__ coef) {
    const int k = blockIdx.x;
    const int o = threadIdx.x;
    __shared__ float reU[64], imU[64];
    reU[o] = uhat[k * 64 + o];
    imU[o] = uhat[4096 + k * 64 + o];
    __syncthreads();
    float zr = 0.f, zi = 0.f;
    #pragma unroll 8
    for (int ii = 0; ii < 64; ++ii) {
        float k0v = Kt[(size_t)(ii * 64 + o) * 64 + k];
        float k1v = Kt[262144 + (size_t)(ii * 64 + o) * 64 + k];
        zr = fmaf(reU[ii], k0v, fmaf(-imU[ii], k1v, zr));
        zi = fmaf(reU[ii], k1v, fmaf(imU[ii], k0v, zi));
    }
    if (k == 0) {
        const int idx = (int)(y[0] * (float)LN);
        float zl = 0.f;
        for (int ii = 0; ii < 64; ++ii)
            zl = fmaf(W[o * 64 + ii], u[(size_t)idx * 64 + ii], zl);
        coef[o] = zr * INV_L;
        coef[4096 + o] = 0.f;
        coef[8192 + o] = zl;
    } else {
        coef[k * 64 + o] = 2.f * zr * INV_L;
        coef[4096 + k * 64 + o] = -2.f * zi * INV_L;
    }
}

// ---------------- K3: inverse via MFMA ----------------
// out[n][ch] = sum_m A[m][ch] cos(2pi n m/L) + B[m][ch] sin(2pi n m/L) + zloc[ch]
// A-matrix (trig) generated per-lane (v_sin/v_cos, revolutions); B = coef staged bf16.
__global__ __launch_bounds__(256) void fno_inv(const float* __restrict__ coef,
                                               float* __restrict__ out) {
    __shared__ __align__(16) unsigned short Bs[64 * 136];  // [ch][mode 0..127]
    __shared__ float zloc[64];
    __shared__ float xpose[4][16 * 68];
    const int tid = threadIdx.x;
    const int lane = tid & 63;
    const int w = tid >> 6;

    for (int e = tid; e < 4096; e += 256) {
        int mm = e >> 6, ch = e & 63;
        Bs[ch * 136 + mm] = f2bf(coef[e]);
        Bs[ch * 136 + 64 + mm] = f2bf(coef[4096 + e]);
    }
    if (tid < 64) zloc[tid] = coef[8192 + tid];
    __syncthreads();

    const int l15 = lane & 15;
    const int hk = lane >> 4;
    const int r0 = lane >> 2;   // output row within 16
    const int cq = lane & 3;    // output quarter (16 channels)
    float4 zv[4];
    #pragma unroll
    for (int uu = 0; uu < 4; ++uu)
        zv[uu] = *(const float4*)&zloc[cq * 16 + uu * 4];

    for (int p = 0; p < 4; ++p) {
        const int nbase = blockIdx.x * 256 + (p * 4 + w) * 16;
        f32x4 acc[4];
        #pragma unroll
        for (int tn = 0; tn < 4; ++tn) acc[tn] = (f32x4){0,0,0,0};

        const int row = nbase + l15;
        #pragma unroll
        for (int ks = 0; ks < 4; ++ks) {
            const int mbase = ks * 32 + hk * 8 - (ks >= 2 ? 64 : 0);  // mode within half
            short8 af;
            int ph = (row * mbase) & LMASK;
            #pragma unroll
            for (int j = 0; j < 8; ++j) {
                float rev = (float)ph * INV_L;
                float v = (ks < 2) ? fcos01(rev) : fsin01(rev);
                af[j] = (short)f2bf(v);
                ph = (ph + row) & LMASK;
            }
            #pragma unroll
            for (int tn = 0; tn < 4; ++tn) {
                const short8 bf = *(const short8*)&Bs[(tn * 16 + l15) * 136 + ks * 32 + hk * 8];
                acc[tn] = __builtin_amdgcn_mfma_f32_16x16x32_bf16(af, bf, acc[tn], 0, 0, 0);
            }
        }
        // wave-local LDS transpose -> fully linear 16B stores
        #pragma unroll
        for (int tn = 0; tn < 4; ++tn)
            #pragma unroll
            for (int r = 0; r < 4; ++r)
                xpose[w][(hk * 4 + r) * 68 + tn * 16 + l15] = acc[tn][r];
        float* po = out + (size_t)(nbase + r0) * NCH;
        #pragma unroll
        for (int uu = 0; uu < 4; ++uu) {
            float4 v = *(const float4*)&xpose[w][r0 * 68 + cq * 16 + uu * 4];
            v.x += zv[uu].x; v.y += zv[uu].y; v.z += zv[uu].z; v.w += zv[uu].w;
            *(float4*)(po + cq * 16 + uu * 4) = v;
        }
    }
}

extern "C" void kernel_launch(void* const* d_in, const int* in_sizes, int n_in,
                              void* d_out, int out_size, void* d_ws, size_t ws_size,
                              hipStream_t stream) {
    const float* u = (const float*)d_in[0];
    const float* y = (const float*)d_in[1];
    const float* K = (const float*)d_in[2];
    const float* W = (const float*)d_in[3];
    float* out = (float*)d_out;
    float* ws = (float*)d_ws;

    int nb = 512;
    while (nb > 64 && ((size_t)(nb * 8192 + 8192 + 8256) * 4) > ws_size) nb >>= 1;

    float* part = ws;                       // nb*8192
    float* uhat = ws + (size_t)nb * 8192;   // 8192
    float* coef = uhat + 8192;              // 8192 + 64

    fno_fwd<<<nb, 256, 0, stream>>>(u, part, nb);
    fno_red<<<64, 256, 0, stream>>>(part, nb, uhat);
    fno_coef<<<64, 64, 0, stream>>>(uhat, K, W, u, y, coef);
    fno_inv<<<1024, 256, 0, stream>>>(coef, out);
}

// Round 4
// 64.718 us; speedup vs baseline: 4.1040x; 1.1355x over previous
//
#include <hip/hip_runtime.h>

#define LN 262144
#define LMASK 262143
#define NCH 64
#define INV_L (1.0f/262144.0f)
#define BSTR 38    // fwd LDS stride (halfs): write<=2-way, read<=2-way banks
#define ISTR 138   // inv Bs stride (halfs): reads <=3-way
#define XSTR 66    // inv xpose stride (floats): ~conflict-free both sides

typedef short short8 __attribute__((ext_vector_type(8)));
typedef float f32x4 __attribute__((ext_vector_type(4)));

static __device__ __forceinline__ unsigned short f2bf(float x) {
    union { float f; unsigned u; } v; v.f = x;
    unsigned r = (v.u + 0x7fff + ((v.u >> 16) & 1)) >> 16;
    return (unsigned short)r;
}
static __device__ __forceinline__ float fsin01(float rev) {  // sin(2*pi*rev)
    float r; asm("v_sin_f32 %0, %1" : "=v"(r) : "v"(rev)); return r;
}
static __device__ __forceinline__ float fcos01(float rev) {  // cos(2*pi*rev)
    float r; asm("v_cos_f32 %0, %1" : "=v"(r) : "v"(rev)); return r;
}

// ---------------- K1: forward DFT partials via MFMA ----------------
// grid: nb x 256 (4 waves). Wave w owns modes 16w..16w+15.
// Double-buffered LDS, 3-deep tile pipeline, 1 barrier per 32-row K-step.
__global__ __launch_bounds__(256) void fno_fwd(const float* __restrict__ u,
                                               float* __restrict__ part, int nb) {
    __shared__ __align__(16) unsigned short Bt[2][64 * BSTR];
    const int tid = threadIdx.x;
    const int lane = tid & 63;
    const int w = tid >> 6;
    const int chunk = LN / nb;
    const int ksteps = chunk >> 5;
    const int n0 = blockIdx.x * chunk;

    const int kkst = tid >> 3;   // staging row 0..31
    const int gst = tid & 7;     // staging channel group

    const int l15 = lane & 15;
    const int hk = lane >> 4;
    const int m = w * 16 + l15;  // this lane's mode

    // rotation state for kk = hk*8 + j, advanced 32 rows per step
    float cR[8], sR[8];
    #pragma unroll
    for (int j = 0; j < 8; ++j) {
        int ph = (m * (n0 + hk * 8 + j)) & LMASK;
        cR[j] = fcos01((float)ph * INV_L);
        sR[j] = fsin01((float)ph * INV_L);
    }
    float cD, sD;
    {
        int ph = (m * 32) & LMASK;
        cD = fcos01((float)ph * INV_L);
        sD = fsin01((float)ph * INV_L);
    }

    f32x4 accC[4], accS[4];
    #pragma unroll
    for (int t = 0; t < 4; ++t) { accC[t] = (f32x4){0,0,0,0}; accS[t] = (f32x4){0,0,0,0}; }

    const float* __restrict__ ub = u + (size_t)(n0 + kkst) * NCH + gst * 8;
    const size_t tstep = 32 * NCH;

    // pipeline: regA = tile to stage next, regB = tile behind it
    float4 a0 = *(const float4*)(ub);
    float4 a1 = *(const float4*)(ub + 4);
    float4 b0 = *(const float4*)(ub + tstep);
    float4 b1 = *(const float4*)(ub + tstep + 4);
    {   // stage tile 0 -> buf 0
        float uv[8] = {a0.x, a0.y, a0.z, a0.w, a1.x, a1.y, a1.z, a1.w};
        #pragma unroll
        for (int q = 0; q < 8; ++q)
            Bt[0][(gst * 8 + q) * BSTR + kkst] = f2bf(uv[q]);
    }
    a0 = b0; a1 = b1;
    b0 = *(const float4*)(ub + 2 * tstep);
    b1 = *(const float4*)(ub + 2 * tstep + 4);

    for (int t = 0; t < ksteps; ++t) {
        __syncthreads();
        if (t + 1 < ksteps) {   // stage tile t+1 (regA) into other buffer
            float uv[8] = {a0.x, a0.y, a0.z, a0.w, a1.x, a1.y, a1.z, a1.w};
            unsigned short* bt = Bt[(t + 1) & 1];
            #pragma unroll
            for (int q = 0; q < 8; ++q)
                bt[(gst * 8 + q) * BSTR + kkst] = f2bf(uv[q]);
        }
        a0 = b0; a1 = b1;
        if (t + 3 < ksteps) {   // prefetch tile t+3
            const float* pn = ub + (size_t)(t + 3) * tstep;
            b0 = *(const float4*)(pn);
            b1 = *(const float4*)(pn + 4);
        }
        // A fragments from rotation state
        short8 aC, aS;
        #pragma unroll
        for (int j = 0; j < 8; ++j) {
            aC[j] = (short)f2bf(cR[j]);
            aS[j] = (short)f2bf(-sR[j]);
        }
        #pragma unroll
        for (int j = 0; j < 8; ++j) {
            float c2 = cR[j] * cD - sR[j] * sD;
            sR[j] = fmaf(sR[j], cD, cR[j] * sD);
            cR[j] = c2;
        }
        const unsigned short* bt = Bt[t & 1];
        #pragma unroll
        for (int tn = 0; tn < 4; ++tn) {
            const short8 bf = *(const short8*)&bt[(tn * 16 + l15) * BSTR + hk * 8];
            accC[tn] = __builtin_amdgcn_mfma_f32_16x16x32_bf16(aC, bf, accC[tn], 0, 0, 0);
            accS[tn] = __builtin_amdgcn_mfma_f32_16x16x32_bf16(aS, bf, accS[tn], 0, 0, 0);
        }
    }
    // C/D: col=lane&15, row=(lane>>4)*4+reg
    float* baseR = part + (size_t)blockIdx.x * 8192;
    #pragma unroll
    for (int tn = 0; tn < 4; ++tn) {
        #pragma unroll
        for (int r = 0; r < 4; ++r) {
            int k = w * 16 + hk * 4 + r;
            int i = tn * 16 + l15;
            baseR[k * 64 + i] = accC[tn][r];
            baseR[4096 + k * 64 + i] = accS[tn][r];
        }
    }
}

// ---------------- K2: reduce partials + apply Kc + z_local ----------------
// grid: 64 blocks (mode k) x 512 threads.
// coef[0..4095]=A(cos), coef[4096..8191]=B(sin), coef[8192..8255]=z_local
__global__ __launch_bounds__(512) void fno_redcoef(const float* __restrict__ part, int nb,
                                                   const float* __restrict__ Kt,
                                                   const float* __restrict__ W,
                                                   const float* __restrict__ u,
                                                   const float* __restrict__ y,
                                                   float* __restrict__ coef) {
    const int k = blockIdx.x;
    const int t = threadIdx.x;
    const int j = t & 127;
    const int h = t >> 7;  // 0..3

    const float* __restrict__ pb = part + (size_t)k * 64 + (j & 63) + ((j >> 6) ? 4096 : 0);
    float s = 0.f;
    #pragma unroll 8
    for (int b = h; b < nb; b += 4)
        s += pb[(size_t)b * 8192];

    __shared__ float red[4][128];
    __shared__ float uh[128];
    red[h][j] = s;
    __syncthreads();
    if (t < 128) uh[t] = red[0][t] + red[1][t] + red[2][t] + red[3][t];
    __syncthreads();

    if (t < 64) {
        const int o = t;
        float zr = 0.f, zi = 0.f;
        #pragma unroll 8
        for (int ii = 0; ii < 64; ++ii) {
            float k0v = Kt[(size_t)(ii * 64 + o) * 64 + k];
            float k1v = Kt[262144 + (size_t)(ii * 64 + o) * 64 + k];
            zr = fmaf(uh[ii], k0v, fmaf(-uh[64 + ii], k1v, zr));
            zi = fmaf(uh[ii], k1v, fmaf(uh[64 + ii], k0v, zi));
        }
        if (k == 0) {
            const int idx = (int)(y[0] * (float)LN);
            float zl = 0.f;
            for (int ii = 0; ii < 64; ++ii)
                zl = fmaf(W[o * 64 + ii], u[(size_t)idx * 64 + ii], zl);
            coef[o] = zr * INV_L;
            coef[4096 + o] = 0.f;
            coef[8192 + o] = zl;
        } else {
            coef[k * 64 + o] = 2.f * zr * INV_L;
            coef[4096 + k * 64 + o] = -2.f * zi * INV_L;
        }
    }
}

// ---------------- K3: inverse via MFMA ----------------
// Trig A-matrix: per (p,half): 1 sincos + 7 complex rotations (cos AND sin
// tiles share the same phase grid). Linear 1KB stores via per-wave xpose.
__global__ __launch_bounds__(256) void fno_inv(const float* __restrict__ coef,
                                               float* __restrict__ out) {
    __shared__ __align__(16) unsigned short Bs[64 * ISTR];  // [ch][cos 0..63 | sin 0..63]
    __shared__ float zloc[64];
    __shared__ float xpose[4][16 * XSTR];
    const int tid = threadIdx.x;
    const int lane = tid & 63;
    const int w = tid >> 6;

    for (int e = tid; e < 4096; e += 256) {
        int mm = e >> 6, ch = e & 63;
        Bs[ch * ISTR + mm] = f2bf(coef[e]);
        Bs[ch * ISTR + 64 + mm] = f2bf(coef[4096 + e]);
    }
    if (tid < 64) zloc[tid] = coef[8192 + tid];
    __syncthreads();

    const int l15 = lane & 15;
    const int hk = lane >> 4;
    const int rl = lane >> 4;        // store: local row quarter
    const int cq = lane & 15;        // store: channel quarter (4 ch)
    float4 zv = *(const float4*)&zloc[cq * 4];

    for (int p = 0; p < 4; ++p) {
        const int nbase = blockIdx.x * 256 + (p * 4 + w) * 16;
        const int row = nbase + l15;
        float cstp = fcos01((float)row * INV_L);
        float sstp = fsin01((float)row * INV_L);

        short8 aF[4];
        #pragma unroll
        for (int h = 0; h < 2; ++h) {
            const int m0 = h * 32 + hk * 8;
            const int ph = (row * m0) & LMASK;
            float c = fcos01((float)ph * INV_L);
            float s = fsin01((float)ph * INV_L);
            #pragma unroll
            for (int jj = 0; jj < 8; ++jj) {
                aF[h][jj] = (short)f2bf(c);
                aF[2 + h][jj] = (short)f2bf(s);
                float c2 = c * cstp - s * sstp;
                s = fmaf(s, cstp, c * sstp);
                c = c2;
            }
        }

        f32x4 acc[4];
        #pragma unroll
        for (int tn = 0; tn < 4; ++tn) acc[tn] = (f32x4){0,0,0,0};
        #pragma unroll
        for (int ks = 0; ks < 4; ++ks) {
            #pragma unroll
            for (int tn = 0; tn < 4; ++tn) {
                const short8 bf = *(const short8*)&Bs[(tn * 16 + l15) * ISTR + ks * 32 + hk * 8];
                acc[tn] = __builtin_amdgcn_mfma_f32_16x16x32_bf16(aF[ks], bf, acc[tn], 0, 0, 0);
            }
        }
        // per-wave transpose -> fully linear stores (1KB per instruction)
        #pragma unroll
        for (int tn = 0; tn < 4; ++tn)
            #pragma unroll
            for (int r = 0; r < 4; ++r)
                xpose[w][(hk * 4 + r) * XSTR + tn * 16 + l15] = acc[tn][r];
        __builtin_amdgcn_s_waitcnt(0);  // wave-local LDS ordering
        #pragma unroll
        for (int rg = 0; rg < 4; ++rg) {
            const int rowl = rg * 4 + rl;
            float4 v = *(const float4*)&xpose[w][rowl * XSTR + cq * 4];
            v.x += zv.x; v.y += zv.y; v.z += zv.z; v.w += zv.w;
            *(float4*)(out + (size_t)(nbase + rowl) * NCH + cq * 4) = v;
        }
    }
}

extern "C" void kernel_launch(void* const* d_in, const int* in_sizes, int n_in,
                              void* d_out, int out_size, void* d_ws, size_t ws_size,
                              hipStream_t stream) {
    const float* u = (const float*)d_in[0];
    const float* y = (const float*)d_in[1];
    const float* K = (const float*)d_in[2];
    const float* W = (const float*)d_in[3];
    float* out = (float*)d_out;
    float* ws = (float*)d_ws;

    int nb = 512;
    while (nb > 64 && ((size_t)(nb * 8192 + 8256) * 4) > ws_size) nb >>= 1;

    float* part = ws;                       // nb*8192
    float* coef = ws + (size_t)nb * 8192;   // 8192 + 64

    fno_fwd<<<nb, 256, 0, stream>>>(u, part, nb);
    fno_redcoef<<<64, 512, 0, stream>>>(part, nb, K, W, u, y, coef);
    fno_inv<<<1024, 256, 0, stream>>>(coef, out);
}